// Round 8
// baseline (1193.564 us; speedup 1.0000x reference)
//
#include <hip/hip_runtime.h>
#include <stdint.h>

typedef __attribute__((ext_vector_type(8))) short short8;
typedef __attribute__((ext_vector_type(4))) float floatx4;

#define P_TOT (16 * 256 * 256)
#define P_IMG 65536
// half-channel tile: 6 x 66 x 40 shorts (32 ch + 8 pad; 80 B row stride)
#define TSTR 40
#define THALF (6 * 66 * TSTR)

__device__ __forceinline__ unsigned short f2bf(float f) {
    unsigned int u = __float_as_uint(f);
    return (unsigned short)((u + 0x7FFFu + ((u >> 16) & 1u)) >> 16);
}
__device__ __forceinline__ float bf2f(unsigned short h) {
    return __uint_as_float(((unsigned int)h) << 16);
}

// ---- repack OIHW fp32 weights -> bf16 MFMA B-fragment order -----------------
__global__ void repack_w(const float* __restrict__ w, unsigned short* __restrict__ bp,
                         int ngroups, int creal) {
    int idx = blockIdx.x * 256 + threadIdx.x;
    if (idx >= ngroups * 9216) return;
    int j = idx & 7;
    int lane = (idx >> 3) & 63;
    int gt = idx >> 9;            // g*18 + t
    int t = gt % 18;
    int n = (gt / 18) * 16 + (lane & 15);
    int tap = t >> 1, hf = t & 1;
    int dy = tap / 3, dx = tap % 3;
    int cin = hf * 32 + (lane >> 4) * 8 + j;
    float v = (n < creal) ? w[((n * 64 + cin) * 3 + dy) * 3 + dx] : 0.f;
    bp[idx] = f2bf(v);
}

// ---- conv3x3 1->64 + bias + relu, fp32 in, bf16 NHWC out --------------------
__global__ __launch_bounds__(256) void conv_1to64(
    const float* __restrict__ x, const float* __restrict__ w,
    const float* __restrict__ b, unsigned short* __restrict__ out) {
    __shared__ float wt[9 * 64];
    __shared__ float bt[64];
    int tid = threadIdx.x;
    for (int i = tid; i < 576; i += 256) {
        int c = i & 63, tap = i >> 6;
        wt[tap * 64 + c] = w[c * 9 + tap];
    }
    if (tid < 64) bt[tid] = b[tid];
    __syncthreads();
    int wi = tid >> 6, c = tid & 63;
    int pix0 = blockIdx.x * 64 + wi * 16;
    int wcol0 = pix0 & 255, hrow = (pix0 >> 8) & 255, n = pix0 >> 16;
    const float* xb = x + ((size_t)n << 16);
    float acc[16];
    float bb = bt[c];
    #pragma unroll
    for (int p = 0; p < 16; p++) acc[p] = bb;
    #pragma unroll
    for (int dy = 0; dy < 3; dy++) {
        int hy = hrow + dy - 1;
        if (hy < 0 || hy > 255) continue;
        const float* rp = xb + (hy << 8) + wcol0;
        float row[18];
        #pragma unroll
        for (int j = 0; j < 18; j++) {
            int gw = wcol0 - 1 + j;
            row[j] = (gw >= 0 && gw < 256) ? rp[j - 1] : 0.f;
        }
        #pragma unroll
        for (int dx = 0; dx < 3; dx++) {
            float wv = wt[(dy * 3 + dx) * 64 + c];
            #pragma unroll
            for (int p = 0; p < 16; p++) acc[p] += row[p + dx] * wv;
        }
    }
    size_t ob = ((size_t)pix0 << 6) + c;
    #pragma unroll
    for (int p = 0; p < 16; p++)
        out[ob + ((size_t)p << 6)] = f2bf(fmaxf(acc[p], 0.f));
}

// ---- conv3x3 2->64 + bias + relu, fp32 [pix][2] in, bf16 NHWC out -----------
__global__ __launch_bounds__(256) void conv_2to64(
    const float* __restrict__ hin, const float* __restrict__ w,
    const float* __restrict__ b, unsigned short* __restrict__ out) {
    __shared__ float wt[18 * 64];
    __shared__ float bt[64];
    int tid = threadIdx.x;
    for (int i = tid; i < 1152; i += 256) {
        int c = i & 63, tc = i >> 6;
        int tap = tc >> 1, ci = tc & 1;
        wt[tc * 64 + c] = w[(c * 2 + ci) * 9 + tap];
    }
    if (tid < 64) bt[tid] = b[tid];
    __syncthreads();
    int wi = tid >> 6, c = tid & 63;
    int pix0 = blockIdx.x * 64 + wi * 16;
    int wcol0 = pix0 & 255, hrow = (pix0 >> 8) & 255, n = pix0 >> 16;
    const float* hb = hin + ((size_t)n << 17);
    float acc[16];
    float bb = bt[c];
    #pragma unroll
    for (int p = 0; p < 16; p++) acc[p] = bb;
    #pragma unroll
    for (int dy = 0; dy < 3; dy++) {
        int hy = hrow + dy - 1;
        if (hy < 0 || hy > 255) continue;
        const float* rp = hb + (((hy << 8) + wcol0) << 1);
        float rx[18], ry[18];
        #pragma unroll
        for (int j = 0; j < 18; j++) {
            int gw = wcol0 - 1 + j;
            bool ok = (gw >= 0 && gw < 256);
            float2 vv = ok ? *(const float2*)(rp + ((j - 1) << 1)) : float2{0.f, 0.f};
            rx[j] = vv.x; ry[j] = vv.y;
        }
        #pragma unroll
        for (int dx = 0; dx < 3; dx++) {
            int tap = dy * 3 + dx;
            float w0 = wt[(tap * 2 + 0) * 64 + c];
            float w1 = wt[(tap * 2 + 1) * 64 + c];
            #pragma unroll
            for (int p = 0; p < 16; p++)
                acc[p] += rx[p + dx] * w0 + ry[p + dx] * w1;
        }
    }
    size_t ob = ((size_t)pix0 << 6) + c;
    #pragma unroll
    for (int p = 0; p < 16; p++)
        out[ob + ((size_t)p << 6)] = f2bf(fmaxf(acc[p], 0.f));
}

// ---- staging helper: load one 32-channel half of the 6x66 halo tile ---------
__device__ __forceinline__ void stage_half(
    unsigned short* tile, const unsigned short* hb, int h0, int w0,
    int tid, int pass) {
    for (int c = tid; c < 6 * 66 * 4; c += 512) {
        int ch = c & 3;
        int cc = (c >> 2) % 66;
        int rr = (c >> 2) / 66;
        int gh = h0 - 1 + rr, gw = w0 - 1 + cc;
        uint4 v = {0u, 0u, 0u, 0u};
        if (gh >= 0 && gh < 256 && gw >= 0 && gw < 256)
            v = *(const uint4*)(hb + (((gh << 8) + gw) << 6) + pass * 32 + ch * 8);
        *(uint4*)(tile + (rr * 66 + cc) * TSTR + ch * 8) = v;
    }
}

// ---- conv3x3 64->NG*16 + bias + relu via MFMA, channel-split K-loop ---------
// 512 threads = 8 waves; wave w: row = w&3, g-half = w>>2. LDS = 31 KB ->
// 4 blocks/CU (32 waves).
template <int NG>
__global__ __launch_bounds__(512, 4) void conv_mfma(
    const unsigned short* __restrict__ hin, const unsigned short* __restrict__ bp,
    const float* __restrict__ bias, unsigned short* __restrict__ hout) {
    constexpr int GH = NG / 2;
    __shared__ __align__(16) unsigned short tile[THALF];
    int blk = blockIdx.x;
    int n = blk >> 8;
    int rem = blk & 255;
    int h0 = (rem >> 2) * 4;
    int w0 = (rem & 3) * 64;
    int tid = threadIdx.x;
    const unsigned short* hb = hin + ((size_t)n << 22);
    int lane = tid & 63, w = tid >> 6;
    int row = w & 3, ghalf = w >> 2;
    int nl = lane & 15, quad = lane >> 4;
    floatx4 acc[4][GH];
    floatx4 zero = {0.f, 0.f, 0.f, 0.f};
    #pragma unroll
    for (int mi = 0; mi < 4; mi++)
        #pragma unroll
        for (int g = 0; g < GH; g++) acc[mi][g] = zero;
    #pragma unroll
    for (int pass = 0; pass < 2; pass++) {
        if (pass) __syncthreads();          // all waves done reading prev half
        stage_half(tile, hb, h0, w0, tid, pass);
        __syncthreads();
        #pragma unroll
        for (int tap = 0; tap < 9; tap++) {
            const int t = tap * 2 + pass;
            const int dy = tap / 3, dx = tap % 3;
            short8 A[4];
            #pragma unroll
            for (int mi = 0; mi < 4; mi++)
                A[mi] = *(const short8*)(tile + ((row + dy) * 66 + mi * 16 + nl + dx) * TSTR + quad * 8);
            #pragma unroll
            for (int g = 0; g < GH; g++) {
                short8 B = *(const short8*)(bp + ((((ghalf * GH + g) * 18 + t) << 6) + lane) * 8);
                #pragma unroll
                for (int mi = 0; mi < 4; mi++)
                    acc[mi][g] = __builtin_amdgcn_mfma_f32_16x16x32_bf16(A[mi], B, acc[mi][g], 0, 0, 0);
            }
        }
    }
    size_t obase = ((size_t)((n * 256 + h0 + row)) << 8) + w0;
    #pragma unroll
    for (int g = 0; g < GH; g++) {
        int gg = ghalf * GH + g;
        float bb = bias[gg * 16 + nl];
        #pragma unroll
        for (int mi = 0; mi < 4; mi++) {
            #pragma unroll
            for (int r = 0; r < 4; r++) {
                int pc = mi * 16 + quad * 4 + r;
                float v = fmaxf(acc[mi][g][r] + bb, 0.f);
                hout[(obase + pc) * (NG * 16) + gg * 16 + nl] = f2bf(v);
            }
        }
    }
}

// ---- conv3x3 64->81 + bias + softmax(81) + 9x9 adaptive filter --------------
// Channel-split K-loop (31 KB tile); logits transposed through LDS in two
// 128-pixel passes; epilogue 4 threads/pixel (24-channel slices).
__global__ __launch_bounds__(512, 4) void conv_softmax_apply(
    const unsigned short* __restrict__ h2b, const unsigned short* __restrict__ bp,
    const float* __restrict__ bias, const float* __restrict__ x,
    float* __restrict__ hout, int head) {
    __shared__ __align__(16) unsigned short tile[THALF];  // reused: logits 128*104
    __shared__ __align__(16) float xt[12 * 72];
    __shared__ float2 pp[512];
    int blk = blockIdx.x;
    int n = blk >> 8;
    int rem = blk & 255;
    int h0 = (rem >> 2) * 4;
    int w0 = (rem & 3) * 64;
    int tid = threadIdx.x;
    const unsigned short* hb = h2b + ((size_t)n << 22);
    const float* xb = x + ((size_t)n << 16);
    for (int c = tid; c < 12 * 72; c += 512) {
        int cc = c % 72, rr = c / 72;
        int gh = h0 - 4 + rr, gw = w0 - 4 + cc;
        xt[c] = (gh >= 0 && gh < 256 && gw >= 0 && gw < 256) ? xb[(gh << 8) + gw] : 0.f;
    }
    int lane = tid & 63, w = tid >> 6;
    int row = w & 3, ghalf = w >> 2;
    int nl = lane & 15, quad = lane >> 4;
    floatx4 acc[4][3];
    floatx4 zero = {0.f, 0.f, 0.f, 0.f};
    #pragma unroll
    for (int mi = 0; mi < 4; mi++)
        #pragma unroll
        for (int g = 0; g < 3; g++) acc[mi][g] = zero;
    #pragma unroll
    for (int pass = 0; pass < 2; pass++) {
        if (pass) __syncthreads();
        stage_half(tile, hb, h0, w0, tid, pass);
        __syncthreads();
        #pragma unroll
        for (int tap = 0; tap < 9; tap++) {
            const int t = tap * 2 + pass;
            const int dy = tap / 3, dx = tap % 3;
            short8 A[4];
            #pragma unroll
            for (int mi = 0; mi < 4; mi++)
                A[mi] = *(const short8*)(tile + ((row + dy) * 66 + mi * 16 + nl + dx) * TSTR + quad * 8);
            #pragma unroll
            for (int g = 0; g < 3; g++) {
                short8 B = *(const short8*)(bp + ((((ghalf * 3 + g) * 18 + t) << 6) + lane) * 8);
                #pragma unroll
                for (int mi = 0; mi < 4; mi++)
                    acc[mi][g] = __builtin_amdgcn_mfma_f32_16x16x32_bf16(A[mi], B, acc[mi][g], 0, 0, 0);
            }
        }
    }
    // two logits passes: rows {0,1} then rows {2,3}
    float bval[3];
    #pragma unroll
    for (int g = 0; g < 3; g++) {
        int ch = (ghalf * 3 + g) * 16 + nl;
        bval[g] = (ch < 81) ? bias[ch] : 0.f;
    }
    #pragma unroll
    for (int half = 0; half < 2; half++) {
        __syncthreads();                 // prior phase's tile reads complete
        if ((row >> 1) == half) {
            #pragma unroll
            for (int g = 0; g < 3; g++) {
                int ch = (ghalf * 3 + g) * 16 + nl;
                #pragma unroll
                for (int mi = 0; mi < 4; mi++) {
                    #pragma unroll
                    for (int r = 0; r < 4; r++) {
                        int pl = (row & 1) * 64 + mi * 16 + quad * 4 + r;  // 0..127
                        tile[pl * 104 + ch] = f2bf(acc[mi][g][r] + bval[g]);
                    }
                }
            }
        }
        __syncthreads();
        // 4 threads per pixel: channel slices [0,24),[24,48),[48,72),[72,81)
        int h = tid >> 7, pl = tid & 127;
        int prow = half * 2 + (pl >> 6), pcol = pl & 63;
        const unsigned short* lgp = tile + pl * 104 + h * 24;
        short8 lg[3];
        #pragma unroll
        for (int jj = 0; jj < 3; jj++) lg[jj] = *(const short8*)(lgp + jj * 8);
        int ch0 = h * 24;
        int cnt = (h == 3) ? 9 : 24;
        float sum = 0.f, dot = 0.f;
        for (int k = 0; k < cnt; k++) {
            int ch = ch0 + k;
            float v = bf2f((unsigned short)lg[k >> 3][k & 7]);
            float e = __expf(v);
            sum += e;
            dot += e * xt[(prow + ch / 9) * 72 + pcol + (ch % 9)];
        }
        pp[tid] = float2{sum, dot};
        __syncthreads();
        if (tid < 128) {
            float2 a = pp[tid], b2 = pp[tid + 128], c2 = pp[tid + 256], d2 = pp[tid + 384];
            float s = a.x + b2.x + c2.x + d2.x;
            float d = a.y + b2.y + c2.y + d2.y;
            size_t gp = ((size_t)((n * 256 + h0 + half * 2 + (tid >> 6))) << 8) + w0 + (tid & 63);
            hout[gp * 2 + head] = d / s;
        }
    }
}

// ---- conv3x3 64->1 + bias via MFMA tile, channel-split K-loop ---------------
__global__ __launch_bounds__(512, 4) void conv_64to1_mfma(
    const unsigned short* __restrict__ h2, const unsigned short* __restrict__ bp,
    const float* __restrict__ b, float* __restrict__ out) {
    __shared__ __align__(16) unsigned short tile[THALF];
    int blk = blockIdx.x;
    int n = blk >> 8;
    int rem = blk & 255;
    int h0 = (rem >> 2) * 4;
    int w0 = (rem & 3) * 64;
    int tid = threadIdx.x;
    const unsigned short* hb = h2 + ((size_t)n << 22);
    int lane = tid & 63, w = tid >> 6;
    int row = w & 3, mh = w >> 2;
    int nl = lane & 15, quad = lane >> 4;
    floatx4 acc[2];
    floatx4 zero = {0.f, 0.f, 0.f, 0.f};
    acc[0] = zero; acc[1] = zero;
    #pragma unroll
    for (int pass = 0; pass < 2; pass++) {
        if (pass) __syncthreads();
        stage_half(tile, hb, h0, w0, tid, pass);
        __syncthreads();
        #pragma unroll
        for (int tap = 0; tap < 9; tap++) {
            const int t = tap * 2 + pass;
            const int dy = tap / 3, dx = tap % 3;
            short8 B = *(const short8*)(bp + ((t << 6) + lane) * 8);
            #pragma unroll
            for (int im = 0; im < 2; im++) {
                int mi = mh * 2 + im;
                short8 A = *(const short8*)(tile + ((row + dy) * 66 + mi * 16 + nl + dx) * TSTR + quad * 8);
                acc[im] = __builtin_amdgcn_mfma_f32_16x16x32_bf16(A, B, acc[im], 0, 0, 0);
            }
        }
    }
    if (nl == 0) {
        float b0 = b[0];
        size_t obase = ((size_t)((n * 256 + h0 + row)) << 8) + w0;
        #pragma unroll
        for (int im = 0; im < 2; im++) {
            int mi = mh * 2 + im;
            #pragma unroll
            for (int r = 0; r < 4; r++)
                out[obase + mi * 16 + quad * 4 + r] = acc[im][r] + b0;
        }
    }
}

extern "C" void kernel_launch(void* const* d_in, const int* in_sizes, int n_in,
                              void* d_out, int out_size, void* d_ws, size_t ws_size,
                              hipStream_t stream) {
    const float* x     = (const float*)d_in[0];
    const float* g     = (const float*)d_in[1];
    const float* fx_w1 = (const float*)d_in[2];
    const float* fx_b1 = (const float*)d_in[3];
    const float* fx_w2 = (const float*)d_in[4];
    const float* fx_b2 = (const float*)d_in[5];
    const float* fx_w3 = (const float*)d_in[6];
    const float* fx_b3 = (const float*)d_in[7];
    const float* fg_w1 = (const float*)d_in[8];
    const float* fg_b1 = (const float*)d_in[9];
    const float* fg_w2 = (const float*)d_in[10];
    const float* fg_b2 = (const float*)d_in[11];
    const float* fg_w3 = (const float*)d_in[12];
    const float* fg_b3 = (const float*)d_in[13];
    const float* c1_w  = (const float*)d_in[14];
    const float* c1_b  = (const float*)d_in[15];
    const float* c2_w  = (const float*)d_in[16];
    const float* c2_b  = (const float*)d_in[17];
    const float* c3_w  = (const float*)d_in[18];
    const float* c3_b  = (const float*)d_in[19];
    float* out = (float*)d_out;

    // ---- adaptive workspace layout ------------------------------------------
    const size_t packElems = 230400;   // 6 packs, bf16 elements
    const size_t fixedB = (size_t)P_TOT * 2 * sizeof(float) + packElems * 2 + 256;
    int c = 16;
    while (c > 1 && fixedB + (size_t)c * P_IMG * 256 > ws_size) c >>= 1;
    size_t pcElems = (size_t)c * P_IMG * 64;

    unsigned short* h1 = (unsigned short*)d_ws;
    unsigned short* h2 = h1 + pcElems;
    float* hin = (float*)(h2 + pcElems);
    unsigned short* bp0 = (unsigned short*)(hin + (size_t)P_TOT * 2);
    unsigned short* bp_w2x = bp0;
    unsigned short* bp_w3x = bp0 + 36864;
    unsigned short* bp_w2g = bp0 + 92160;
    unsigned short* bp_w3g = bp0 + 129024;
    unsigned short* bp_c2  = bp0 + 184320;
    unsigned short* bp_c3  = bp0 + 221184;

    dim3 blk(256);
    dim3 blk512(512);
    repack_w<<<144, blk, 0, stream>>>(fx_w2, bp_w2x, 4, 64);
    repack_w<<<216, blk, 0, stream>>>(fx_w3, bp_w3x, 6, 81);
    repack_w<<<144, blk, 0, stream>>>(fg_w2, bp_w2g, 4, 64);
    repack_w<<<216, blk, 0, stream>>>(fg_w3, bp_w3g, 6, 81);
    repack_w<<<144, blk, 0, stream>>>(c2_w,  bp_c2,  4, 64);
    repack_w<<<36,  blk, 0, stream>>>(c3_w,  bp_c3,  1, 1);

    const int nchunk = 16 / c;
    for (int ck = 0; ck < nchunk; ck++) {
        size_t po = (size_t)ck * c * P_IMG;
        conv_1to64<<<c * P_IMG / 64, blk, 0, stream>>>(x + po, fx_w1, fx_b1, h1);
        conv_mfma<4><<<c * 256, blk512, 0, stream>>>(h1, bp_w2x, fx_b2, h2);
        conv_softmax_apply<<<c * 256, blk512, 0, stream>>>(h2, bp_w3x, fx_b3, x + po, hin + po * 2, 0);
    }
    for (int ck = 0; ck < nchunk; ck++) {
        size_t po = (size_t)ck * c * P_IMG;
        conv_1to64<<<c * P_IMG / 64, blk, 0, stream>>>(g + po, fg_w1, fg_b1, h1);
        conv_mfma<4><<<c * 256, blk512, 0, stream>>>(h1, bp_w2g, fg_b2, h2);
        conv_softmax_apply<<<c * 256, blk512, 0, stream>>>(h2, bp_w3g, fg_b3, g + po, hin + po * 2, 1);
    }
    for (int ck = 0; ck < nchunk; ck++) {
        size_t po = (size_t)ck * c * P_IMG;
        conv_2to64<<<c * P_IMG / 64, blk, 0, stream>>>(hin + po * 2, c1_w, c1_b, h1);
        conv_mfma<4><<<c * 256, blk512, 0, stream>>>(h1, bp_c2, c2_b, h2);
        conv_64to1_mfma<<<c * 256, blk512, 0, stream>>>(h2, bp_c3, c3_b, out + po);
    }
}